// Round 3
// baseline (347.309 us; speedup 1.0000x reference)
//
#include <hip/hip_runtime.h>
#include <hip/hip_bf16.h>

constexpr int Bn = 64;
constexpr int Ln = 2048;
constexpr int Dn = 128;
constexpr int Hn = 4;
constexpr int An = 128;
constexpr int Mn = 16;
constexpr int Vn = 100000;
constexpr int HDn = 32;
constexpr float GAMMA = 0.3f;
constexpr float BETA = 1.0f;

// workspace layout (in floats); all offsets are multiples of 4 -> 16B aligned
constexpr size_t OFF_PHIP  = 0;                     // 16*128   = 2048
constexpr size_t OFF_SIZEP = 2048;                  // 16
constexpr size_t OFF_PHIQ  = 2064;                  // 64*128   = 8192
constexpr size_t OFF_SUMPS = 10256;                 // 64*16    = 1024
constexpr size_t OFF_C     = 11280;                 // 64*4*128 = 32768
constexpr size_t OFF_PT    = 44048;                 // V*16     = 1600000
constexpr size_t WS_FLOATS_NEEDED = OFF_PT + (size_t)Vn * 16;

__device__ __forceinline__ float sigm(float x) { return 1.f / (1.f + __expf(-x)); }

// ---------------------------------------------------------------------------
// K1: PhiP[m,a] = sum_v sigmoid(phi[m,v]) * E[v,a]; writes pT[v,m]; sizeP[m].
// One 128-row chunk per block (grid = ceil(V/128) = 782). Zero-redundancy:
// thread t owns float4 column a4 = t&31 and v-stripe sub = t>>5, accumulating
// ALL 16 m in registers (16 float4 = 64 VGPRs). Every E load is a unique line.
// ---------------------------------------------------------------------------
__global__ __launch_bounds__(256) void k_phip(const float* __restrict__ phi,
                                              const float* __restrict__ E,
                                              float* __restrict__ PhiP,
                                              float* __restrict__ sizeP,
                                              float* __restrict__ pT,
                                              int write_pT) {
    __shared__ float pv[128 * 16];            // pv[v*16 + m]
    __shared__ float4 red[4 * Mn * 32];       // [wave][m][a4]
    __shared__ float szl[Mn];
    const int t = threadIdx.x;
    const int v0 = (int)blockIdx.x * 128;
    const int nvalid = min(128, Vn - v0);     // rows in this chunk

    if (t < Mn) szl[t] = 0.f;
    __syncthreads();

    // ---- fill: thread t -> local row vl = t>>1, m-range mb..mb+7 (mb = 8*(t&1))
    {
        const int vl = t >> 1;
        const int mb = 8 * (t & 1);
        float4 p0 = make_float4(0.f, 0.f, 0.f, 0.f);
        float4 p1 = make_float4(0.f, 0.f, 0.f, 0.f);
        if (vl < nvalid) {
            const int v = v0 + vl;
            p0.x = sigm(phi[(size_t)(mb + 0) * Vn + v]);
            p0.y = sigm(phi[(size_t)(mb + 1) * Vn + v]);
            p0.z = sigm(phi[(size_t)(mb + 2) * Vn + v]);
            p0.w = sigm(phi[(size_t)(mb + 3) * Vn + v]);
            p1.x = sigm(phi[(size_t)(mb + 4) * Vn + v]);
            p1.y = sigm(phi[(size_t)(mb + 5) * Vn + v]);
            p1.z = sigm(phi[(size_t)(mb + 6) * Vn + v]);
            p1.w = sigm(phi[(size_t)(mb + 7) * Vn + v]);
            if (write_pT) {
                *(float4*)&pT[(size_t)v * 16 + mb + 0] = p0;
                *(float4*)&pT[(size_t)v * 16 + mb + 4] = p1;
            }
            // per-m size partials (16 LDS addresses, contention hidden by waves)
            atomicAdd(&szl[mb + 0], p0.x); atomicAdd(&szl[mb + 1], p0.y);
            atomicAdd(&szl[mb + 2], p0.z); atomicAdd(&szl[mb + 3], p0.w);
            atomicAdd(&szl[mb + 4], p1.x); atomicAdd(&szl[mb + 5], p1.y);
            atomicAdd(&szl[mb + 6], p1.z); atomicAdd(&szl[mb + 7], p1.w);
        }
        *(float4*)&pv[vl * 16 + mb + 0] = p0;
        *(float4*)&pv[vl * 16 + mb + 4] = p1;
    }
    __syncthreads();

    // ---- compute: acc[m] += p[m,v] * E[v, a4*4..]
    const int a4 = t & 31;
    const int sub = t >> 5;
    float4 acc[Mn];
#pragma unroll
    for (int m = 0; m < Mn; ++m) acc[m] = make_float4(0.f, 0.f, 0.f, 0.f);

    const float4* E4 = (const float4*)E + (size_t)v0 * 32 + a4;
    if (nvalid == 128) {
#pragma unroll 4
        for (int v = sub; v < 128; v += 8) {
            const float4 e = E4[(size_t)v * 32];
            const float4 q0 = *(const float4*)&pv[v * 16 + 0];
            const float4 q1 = *(const float4*)&pv[v * 16 + 4];
            const float4 q2 = *(const float4*)&pv[v * 16 + 8];
            const float4 q3 = *(const float4*)&pv[v * 16 + 12];
            acc[0].x += q0.x * e.x; acc[0].y += q0.x * e.y; acc[0].z += q0.x * e.z; acc[0].w += q0.x * e.w;
            acc[1].x += q0.y * e.x; acc[1].y += q0.y * e.y; acc[1].z += q0.y * e.z; acc[1].w += q0.y * e.w;
            acc[2].x += q0.z * e.x; acc[2].y += q0.z * e.y; acc[2].z += q0.z * e.z; acc[2].w += q0.z * e.w;
            acc[3].x += q0.w * e.x; acc[3].y += q0.w * e.y; acc[3].z += q0.w * e.z; acc[3].w += q0.w * e.w;
            acc[4].x += q1.x * e.x; acc[4].y += q1.x * e.y; acc[4].z += q1.x * e.z; acc[4].w += q1.x * e.w;
            acc[5].x += q1.y * e.x; acc[5].y += q1.y * e.y; acc[5].z += q1.y * e.z; acc[5].w += q1.y * e.w;
            acc[6].x += q1.z * e.x; acc[6].y += q1.z * e.y; acc[6].z += q1.z * e.z; acc[6].w += q1.z * e.w;
            acc[7].x += q1.w * e.x; acc[7].y += q1.w * e.y; acc[7].z += q1.w * e.z; acc[7].w += q1.w * e.w;
            acc[8].x += q2.x * e.x; acc[8].y += q2.x * e.y; acc[8].z += q2.x * e.z; acc[8].w += q2.x * e.w;
            acc[9].x += q2.y * e.x; acc[9].y += q2.y * e.y; acc[9].z += q2.y * e.z; acc[9].w += q2.y * e.w;
            acc[10].x += q2.z * e.x; acc[10].y += q2.z * e.y; acc[10].z += q2.z * e.z; acc[10].w += q2.z * e.w;
            acc[11].x += q2.w * e.x; acc[11].y += q2.w * e.y; acc[11].z += q2.w * e.z; acc[11].w += q2.w * e.w;
            acc[12].x += q3.x * e.x; acc[12].y += q3.x * e.y; acc[12].z += q3.x * e.z; acc[12].w += q3.x * e.w;
            acc[13].x += q3.y * e.x; acc[13].y += q3.y * e.y; acc[13].z += q3.y * e.z; acc[13].w += q3.y * e.w;
            acc[14].x += q3.z * e.x; acc[14].y += q3.z * e.y; acc[14].z += q3.z * e.z; acc[14].w += q3.z * e.w;
            acc[15].x += q3.w * e.x; acc[15].y += q3.w * e.y; acc[15].z += q3.w * e.z; acc[15].w += q3.w * e.w;
        }
    } else {
        for (int v = sub; v < nvalid; v += 8) {
            const float4 e = E4[(size_t)v * 32];
#pragma unroll
            for (int m = 0; m < Mn; ++m) {
                const float pm = pv[v * 16 + m];
                acc[m].x += pm * e.x; acc[m].y += pm * e.y;
                acc[m].z += pm * e.z; acc[m].w += pm * e.w;
            }
        }
    }
    __syncthreads();   // done reading pv / szl filled

    // ---- reduce sub pairs within wave (lanes l and l^32 share a4)
#pragma unroll
    for (int m = 0; m < Mn; ++m) {
        acc[m].x += __shfl_xor(acc[m].x, 32);
        acc[m].y += __shfl_xor(acc[m].y, 32);
        acc[m].z += __shfl_xor(acc[m].z, 32);
        acc[m].w += __shfl_xor(acc[m].w, 32);
    }
    const int lane = t & 63, wv = t >> 6;
    if (lane < 32) {
#pragma unroll
        for (int m = 0; m < Mn; ++m)
            red[(wv * Mn + m) * 32 + a4] = acc[m];
    }
    __syncthreads();

    // ---- final: 512 float4 outputs, 2 per thread; sum 4 waves, global atomics
#pragma unroll
    for (int r = 0; r < 2; ++r) {
        const int idx = t + r * 256;          // 0..511
        const int m = idx >> 5, a = idx & 31;
        const float4 s0 = red[(0 * Mn + m) * 32 + a];
        const float4 s1 = red[(1 * Mn + m) * 32 + a];
        const float4 s2 = red[(2 * Mn + m) * 32 + a];
        const float4 s3 = red[(3 * Mn + m) * 32 + a];
        float* dst = &PhiP[(size_t)m * An + a * 4];
        atomicAdd(dst + 0, s0.x + s1.x + s2.x + s3.x);
        atomicAdd(dst + 1, s0.y + s1.y + s2.y + s3.y);
        atomicAdd(dst + 2, s0.z + s1.z + s2.z + s3.z);
        atomicAdd(dst + 3, s0.w + s1.w + s2.w + s3.w);
    }
    if (t < Mn) atomicAdd(&sizeP[t], szl[t]);
}

// ---------------------------------------------------------------------------
// K2: PhiQ[b,a] = sum_{i in seg b} E[qid[i],a];  sumpS[b,m] = sum_i pT[qid[i],m]
// grid (64 splits, B). block 256. Unroll-by-4 index prefetch, LDS staging.
// ---------------------------------------------------------------------------
__global__ __launch_bounds__(256) void k_phiq(const int* __restrict__ qid,
                                              const int* __restrict__ offs,
                                              const float* __restrict__ E,
                                              const float* __restrict__ phi,
                                              const float* __restrict__ pT,
                                              int usepT,
                                              float* __restrict__ PhiQ,
                                              float* __restrict__ sumpS) {
    const int b = blockIdx.y;
    const int s0 = offs[b], s1 = offs[b + 1];
    const int len = s1 - s0;
    const int nsplit = (int)gridDim.x;
    const int chunk = (len + nsplit - 1) / nsplit;
    const int start = s0 + (int)blockIdx.x * chunk;
    const int end = min(start + chunk, s1);
    const int t = threadIdx.x;

    __shared__ float phl[8 * 128];
    __shared__ float sP[Mn];
    if (t < Mn) sP[t] = 0.f;

    // --- Phase 1: PhiQ. 8 entries in flight (32 lanes/entry), unroll 4.
    {
        const int a4 = t & 31, sub = t >> 5;
        float4 acc = make_float4(0.f, 0.f, 0.f, 0.f);
        const float4* E4 = (const float4*)E;
        int i = start + sub;
        for (; i + 24 < end; i += 32) {
            const int q0 = qid[i], q1 = qid[i + 8], q2 = qid[i + 16], q3 = qid[i + 24];
            const float4 e0 = E4[(size_t)q0 * 32 + a4];
            const float4 e1 = E4[(size_t)q1 * 32 + a4];
            const float4 e2 = E4[(size_t)q2 * 32 + a4];
            const float4 e3 = E4[(size_t)q3 * 32 + a4];
            acc.x += e0.x + e1.x + e2.x + e3.x;
            acc.y += e0.y + e1.y + e2.y + e3.y;
            acc.z += e0.z + e1.z + e2.z + e3.z;
            acc.w += e0.w + e1.w + e2.w + e3.w;
        }
        for (; i < end; i += 8) {
            const float4 e = E4[(size_t)qid[i] * 32 + a4];
            acc.x += e.x; acc.y += e.y; acc.z += e.z; acc.w += e.w;
        }
        *(float4*)&phl[sub * 128 + a4 * 4] = acc;
    }
    __syncthreads();
    if (t < 128) {
        float s = 0.f;
#pragma unroll
        for (int k = 0; k < 8; ++k) s += phl[k * 128 + t];
        atomicAdd(&PhiQ[(size_t)b * An + t], s);
    }

    // --- Phase 2: sumpS. 64 entries in flight (4 lanes/entry), unroll 4.
    float4 acc = make_float4(0.f, 0.f, 0.f, 0.f);
    const int m4 = t & 3, io = t >> 2;
    if (usepT) {
        const float4* pT4 = (const float4*)pT;
        int i = start + io;
        for (; i + 192 < end; i += 256) {
            const int q0 = qid[i], q1 = qid[i + 64], q2 = qid[i + 128], q3 = qid[i + 192];
            const float4 p0 = pT4[(size_t)q0 * 4 + m4];
            const float4 p1 = pT4[(size_t)q1 * 4 + m4];
            const float4 p2 = pT4[(size_t)q2 * 4 + m4];
            const float4 p3 = pT4[(size_t)q3 * 4 + m4];
            acc.x += p0.x + p1.x + p2.x + p3.x;
            acc.y += p0.y + p1.y + p2.y + p3.y;
            acc.z += p0.z + p1.z + p2.z + p3.z;
            acc.w += p0.w + p1.w + p2.w + p3.w;
        }
        for (; i < end; i += 64) {
            const float4 p = pT4[(size_t)qid[i] * 4 + m4];
            acc.x += p.x; acc.y += p.y; acc.z += p.z; acc.w += p.w;
        }
    } else {
        for (int i = start + io; i < end; i += 64) {
            const int q = qid[i];
            acc.x += sigm(phi[(size_t)(m4 * 4 + 0) * Vn + q]);
            acc.y += sigm(phi[(size_t)(m4 * 4 + 1) * Vn + q]);
            acc.z += sigm(phi[(size_t)(m4 * 4 + 2) * Vn + q]);
            acc.w += sigm(phi[(size_t)(m4 * 4 + 3) * Vn + q]);
        }
    }
#pragma unroll
    for (int off = 32; off >= 4; off >>= 1) {
        acc.x += __shfl_xor(acc.x, off);
        acc.y += __shfl_xor(acc.y, off);
        acc.z += __shfl_xor(acc.z, off);
        acc.w += __shfl_xor(acc.w, off);
    }
    if ((t & 63) < 4) {
        atomicAdd(&sP[m4 * 4 + 0], acc.x);
        atomicAdd(&sP[m4 * 4 + 1], acc.y);
        atomicAdd(&sP[m4 * 4 + 2], acc.z);
        atomicAdd(&sP[m4 * 4 + 3], acc.w);
    }
    __syncthreads();
    if (t < Mn) atomicAdd(&sumpS[(size_t)b * Mn + t], sP[t]);
}

// ---------------------------------------------------------------------------
// K3: per-b block (128 thr): BP, Vp, AQ, scores, softmax, Z, C[b,h,:]
// ---------------------------------------------------------------------------
__global__ __launch_bounds__(128) void k_small(const float* __restrict__ PhiP,
                                               const float* __restrict__ sizeP,
                                               const float* __restrict__ PhiQ,
                                               const float* __restrict__ sumpS,
                                               const int* __restrict__ offs,
                                               const float* __restrict__ W_A,
                                               const float* __restrict__ W_B,
                                               const float* __restrict__ W_val,
                                               const float* __restrict__ b_val,
                                               const float* __restrict__ W_out,
                                               const float* __restrict__ size_w,
                                               float* __restrict__ Cws) {
    const int b = blockIdx.x;
    const int i = threadIdx.x;
    __shared__ float BP[Mn * An];
    __shared__ float Vp[Mn * HDn];
    __shared__ float AQs[An];
    __shared__ float sc[Mn];
    __shared__ float attn[Mn];
    __shared__ float Zs[HDn];

    {
        const float4* wa = (const float4*)(W_A + (size_t)i * An);
        const float4* pq = (const float4*)(PhiQ + (size_t)b * An);
        float aq = 0.f;
        for (int q = 0; q < An / 4; ++q) {
            const float4 w = wa[q], p = pq[q];
            aq += w.x * p.x + w.y * p.y + w.z * p.z + w.w * p.w;
        }
        AQs[i] = aq;
    }
    {
        const float4* wb = (const float4*)(W_B + (size_t)i * An);
        for (int m = 0; m < Mn; ++m) {
            const float4* pp = (const float4*)(PhiP + (size_t)m * An);
            float s = 0.f;
            for (int q = 0; q < An / 4; ++q) {
                const float4 w = wb[q], p = pp[q];
                s += w.x * p.x + w.y * p.y + w.z * p.z + w.w * p.w;
            }
            BP[m * An + i] = s;
        }
    }
    if (i < HDn) {
        const float4* wv = (const float4*)(W_val + (size_t)i * An);
        for (int m = 0; m < Mn; ++m) {
            const float4* pp = (const float4*)(PhiP + (size_t)m * An);
            float s = 0.f;
            for (int q = 0; q < An / 4; ++q) {
                const float4 w = wv[q], p = pp[q];
                s += w.x * p.x + w.y * p.y + w.z * p.z + w.w * p.w;
            }
            Vp[m * HDn + i] = s + b_val[i];
        }
    }
    __syncthreads();

    const float szQ = (float)(offs[b + 1] - offs[b]);
    if (i < Mn) {
        float d = 0.f;
        for (int a = 0; a < An; ++a) d += AQs[a] * BP[i * An + a];
        const float delta = szQ + sizeP[i] - 2.f * sumpS[(size_t)b * Mn + i];
        sc[i] = -GAMMA * delta + BETA * d + size_w[0] * szQ + size_w[1] * sizeP[i];
    }
    __syncthreads();
    if (i < Mn) {
        float mx = sc[0];
        for (int m = 1; m < Mn; ++m) mx = fmaxf(mx, sc[m]);
        float sum = 0.f;
        for (int m = 0; m < Mn; ++m) sum += __expf(sc[m] - mx);
        attn[i] = __expf(sc[i] - mx) / sum;
    }
    __syncthreads();
    if (i < HDn) {
        float z = 0.f;
        for (int m = 0; m < Mn; ++m) z += attn[m] * Vp[m * HDn + i];
        Zs[i] = z;
    }
    __syncthreads();
    {
        const float* wo = W_out + (size_t)i * Dn;
#pragma unroll
        for (int h = 0; h < Hn; ++h) {
            float c = 0.f;
#pragma unroll
            for (int j = 0; j < HDn; ++j) c += Zs[j] * wo[h * HDn + j];
            Cws[((size_t)b * Hn + h) * Dn + i] = c;
        }
    }
}

// ---------------------------------------------------------------------------
// K4: out[b,l,:] = b_out + sum_h softmax_h(ts[b,l,:].W_gate[h]+b_gate) * C[b,h,:]
// ---------------------------------------------------------------------------
__global__ __launch_bounds__(256) void k_out(const float* __restrict__ ts,
                                             const float* __restrict__ W_gate,
                                             const float* __restrict__ b_gate,
                                             const float* __restrict__ b_out,
                                             const float* __restrict__ Cws,
                                             float* __restrict__ out) {
    constexpr int CHUNK = 128;
    const int b = blockIdx.y;
    const int t = threadIdx.x;
    __shared__ float4 WgS[Hn * 32];
    __shared__ float4 CS[Hn * 32];
    __shared__ float4 boS[32];
    __shared__ float bgS[Hn];
    if (t < 128) WgS[t] = ((const float4*)W_gate)[t];
    else CS[t - 128] = ((const float4*)(Cws + (size_t)b * Hn * Dn))[t - 128];
    if (t < 32) boS[t] = ((const float4*)b_out)[t];
    if (t >= 64 && t < 64 + Hn) bgS[t - 64] = b_gate[t - 64];
    __syncthreads();

    const int sl = t & 31;
    const int tg = t >> 5;
    const size_t rowbase = (size_t)b * Ln + (size_t)blockIdx.x * CHUNK;
    const float4* x4 = (const float4*)ts + rowbase * 32;
    float4* o4 = (float4*)out + rowbase * 32;

    const float4 w0 = WgS[0 * 32 + sl], w1 = WgS[1 * 32 + sl];
    const float4 w2 = WgS[2 * 32 + sl], w3 = WgS[3 * 32 + sl];
    const float4 c0 = CS[0 * 32 + sl], c1 = CS[1 * 32 + sl];
    const float4 c2 = CS[2 * 32 + sl], c3 = CS[3 * 32 + sl];
    const float4 bo = boS[sl];
    const float bg0 = bgS[0], bg1 = bgS[1], bg2 = bgS[2], bg3 = bgS[3];

    for (int it = 0; it < CHUNK / 8; ++it) {
        const int tok = it * 8 + tg;
        const float4 x = x4[(size_t)tok * 32 + sl];
        float a0 = x.x * w0.x + x.y * w0.y + x.z * w0.z + x.w * w0.w;
        float a1 = x.x * w1.x + x.y * w1.y + x.z * w1.z + x.w * w1.w;
        float a2 = x.x * w2.x + x.y * w2.y + x.z * w2.z + x.w * w2.w;
        float a3 = x.x * w3.x + x.y * w3.y + x.z * w3.z + x.w * w3.w;
#pragma unroll
        for (int off = 16; off > 0; off >>= 1) {
            a0 += __shfl_xor(a0, off);
            a1 += __shfl_xor(a1, off);
            a2 += __shfl_xor(a2, off);
            a3 += __shfl_xor(a3, off);
        }
        a0 += bg0; a1 += bg1; a2 += bg2; a3 += bg3;
        const float mx = fmaxf(fmaxf(a0, a1), fmaxf(a2, a3));
        const float e0 = __expf(a0 - mx), e1 = __expf(a1 - mx);
        const float e2 = __expf(a2 - mx), e3 = __expf(a3 - mx);
        const float inv = 1.f / (e0 + e1 + e2 + e3);
        const float g0 = e0 * inv, g1 = e1 * inv, g2 = e2 * inv, g3 = e3 * inv;
        float4 o = bo;
        o.x += g0 * c0.x + g1 * c1.x + g2 * c2.x + g3 * c3.x;
        o.y += g0 * c0.y + g1 * c1.y + g2 * c2.y + g3 * c3.y;
        o.z += g0 * c0.z + g1 * c1.z + g2 * c2.z + g3 * c3.z;
        o.w += g0 * c0.w + g1 * c1.w + g2 * c2.w + g3 * c3.w;
        o4[(size_t)tok * 32 + sl] = o;
    }
}

extern "C" void kernel_launch(void* const* d_in, const int* in_sizes, int n_in,
                              void* d_out, int out_size, void* d_ws, size_t ws_size,
                              hipStream_t stream) {
    const float* ts     = (const float*)d_in[0];
    const int*   qid    = (const int*)d_in[1];
    const int*   offs   = (const int*)d_in[2];
    const float* E      = (const float*)d_in[3];
    const float* phi    = (const float*)d_in[4];
    const float* W_A    = (const float*)d_in[5];
    const float* W_B    = (const float*)d_in[6];
    const float* W_val  = (const float*)d_in[7];
    const float* b_val  = (const float*)d_in[8];
    const float* W_gate = (const float*)d_in[9];
    const float* b_gate = (const float*)d_in[10];
    const float* W_out  = (const float*)d_in[11];
    const float* b_out  = (const float*)d_in[12];
    const float* size_w = (const float*)d_in[13];
    float* out = (float*)d_out;
    float* ws  = (float*)d_ws;

    float* PhiP  = ws + OFF_PHIP;
    float* sizeP = ws + OFF_SIZEP;
    float* PhiQ  = ws + OFF_PHIQ;
    float* sumpS = ws + OFF_SUMPS;
    float* Cws   = ws + OFF_C;
    float* pT    = ws + OFF_PT;
    const int usepT = (ws_size >= WS_FLOATS_NEEDED * sizeof(float)) ? 1 : 0;

    hipMemsetAsync(ws, 0, OFF_C * sizeof(float), stream);  // zero accumulators
    k_phip<<<dim3((Vn + 127) / 128), dim3(256), 0, stream>>>(phi, E, PhiP, sizeP, pT, usepT);
    k_phiq<<<dim3(64, Bn), dim3(256), 0, stream>>>(qid, offs, E, phi, pT, usepT, PhiQ, sumpS);
    k_small<<<dim3(Bn), dim3(128), 0, stream>>>(PhiP, sizeP, PhiQ, sumpS, offs,
                                                W_A, W_B, W_val, b_val, W_out, size_w, Cws);
    k_out<<<dim3(Ln / 128, Bn), dim3(256), 0, stream>>>(ts, W_gate, b_gate, b_out, Cws, out);
}

// Round 4
// 316.530 us; speedup vs baseline: 1.0972x; 1.0972x over previous
//
#include <hip/hip_runtime.h>
#include <hip/hip_bf16.h>

constexpr int Bn = 64;
constexpr int Ln = 2048;
constexpr int Dn = 128;
constexpr int Hn = 4;
constexpr int An = 128;
constexpr int Mn = 16;
constexpr int Vn = 100000;
constexpr int HDn = 32;
constexpr float GAMMA = 0.3f;
constexpr float BETA = 1.0f;

constexpr int PHIP_BLOCKS = 1024;   // k_phip grid; also k_red's reduction depth

// workspace layout (in floats); all offsets are multiples of 4 -> 16B aligned
constexpr size_t OFF_PHIP  = 0;                     // 16*128   = 2048
constexpr size_t OFF_SIZEP = 2048;                  // 16
constexpr size_t OFF_PHIQ  = 2064;                  // 64*128   = 8192
constexpr size_t OFF_SUMPS = 10256;                 // 64*16    = 1024
constexpr size_t OFF_C     = 11280;                 // 64*4*128 = 32768
constexpr size_t OFF_PT    = 44048;                 // V*16     = 1600000
constexpr size_t OFF_PART  = OFF_PT + (size_t)Vn * 16;          // 1644048
constexpr size_t WS_FLOATS_PT   = OFF_PART;                      // pT tier
constexpr size_t WS_FLOATS_PART = OFF_PART + (size_t)PHIP_BLOCKS * Mn * An;  // partials tier

__device__ __forceinline__ float sigm(float x) { return 1.f / (1.f + __expf(-x)); }

// ---------------------------------------------------------------------------
// K0: pT[v,m] = sigmoid(phi[m,v]); sizeP[m] = sum_v.  grid ceil(V/256) x 256.
// ---------------------------------------------------------------------------
__global__ __launch_bounds__(256) void k_pt(const float* __restrict__ phi,
                                            float* __restrict__ pT,
                                            float* __restrict__ sizeP) {
    __shared__ float szl[Mn];
    const int t = threadIdx.x;
    if (t < Mn) szl[t] = 0.f;
    __syncthreads();
    const int v = (int)blockIdx.x * 256 + t;
    if (v < Vn) {
        float p[Mn];
#pragma unroll
        for (int m = 0; m < Mn; ++m) p[m] = sigm(phi[(size_t)m * Vn + v]);
        float4* dst = (float4*)&pT[(size_t)v * 16];
        dst[0] = make_float4(p[0], p[1], p[2], p[3]);
        dst[1] = make_float4(p[4], p[5], p[6], p[7]);
        dst[2] = make_float4(p[8], p[9], p[10], p[11]);
        dst[3] = make_float4(p[12], p[13], p[14], p[15]);
#pragma unroll
        for (int m = 0; m < Mn; ++m) atomicAdd(&szl[m], p[m]);
    }
    __syncthreads();
    if (t < Mn) atomicAdd(&sizeP[t], szl[t]);
}

// ---------------------------------------------------------------------------
// K1: PhiP[m,a] = sum_v pT[v,m] * E[v,a].
// 1024 blocks x 256. Wave-centric grid-stride over row-PAIRS of E: lane owns
// row rh=lane>>5, float4 col c=lane&31 -> each wave-iter consumes a unique
// contiguous 1 KB of E. p-values via 4 float4 loads from pT (L1 broadcast).
// Depth-2 software pipeline; 16 float4 acc in regs; NO LDS in main loop.
// mode 0: write per-block partials (k_red sums them). mode 1: global atomics.
// ---------------------------------------------------------------------------
__global__ __launch_bounds__(256, 4) void k_phip(const float* __restrict__ E,
                                                 const float* __restrict__ pT,
                                                 float* __restrict__ PhiP,
                                                 float* __restrict__ part,
                                                 int mode) {
    const int t = threadIdx.x;
    const int wv = t >> 6, lane = t & 63;
    const int c = lane & 31;      // float4 column of E row
    const int rh = lane >> 5;     // row within pair
    const int W = (int)gridDim.x * 4;
    const int w = (int)blockIdx.x * 4 + wv;
    constexpr int NP = Vn / 2;    // 50000 row-pairs

    const float4* E4 = (const float4*)E;
    const float4* P4 = (const float4*)pT;

    float4 acc[Mn];
#pragma unroll
    for (int m = 0; m < Mn; ++m) acc[m] = make_float4(0.f, 0.f, 0.f, 0.f);

    int i = w;
    float4 e_n = make_float4(0.f, 0.f, 0.f, 0.f);
    float4 pf_n0 = e_n, pf_n1 = e_n, pf_n2 = e_n, pf_n3 = e_n;
    if (i < NP) {
        const size_t vr = (size_t)(2 * i + rh);
        e_n = E4[vr * 32 + c];
        pf_n0 = P4[vr * 4 + 0]; pf_n1 = P4[vr * 4 + 1];
        pf_n2 = P4[vr * 4 + 2]; pf_n3 = P4[vr * 4 + 3];
    }
    while (i < NP) {
        const float4 e = e_n;
        const float4 f0 = pf_n0, f1 = pf_n1, f2 = pf_n2, f3 = pf_n3;
        const int in = i + W;
        if (in < NP) {   // issue next-iteration loads before using current
            const size_t vr = (size_t)(2 * in + rh);
            e_n = E4[vr * 32 + c];
            pf_n0 = P4[vr * 4 + 0]; pf_n1 = P4[vr * 4 + 1];
            pf_n2 = P4[vr * 4 + 2]; pf_n3 = P4[vr * 4 + 3];
        }
        float pm[Mn];
        pm[0] = f0.x; pm[1] = f0.y; pm[2] = f0.z; pm[3] = f0.w;
        pm[4] = f1.x; pm[5] = f1.y; pm[6] = f1.z; pm[7] = f1.w;
        pm[8] = f2.x; pm[9] = f2.y; pm[10] = f2.z; pm[11] = f2.w;
        pm[12] = f3.x; pm[13] = f3.y; pm[14] = f3.z; pm[15] = f3.w;
#pragma unroll
        for (int m = 0; m < Mn; ++m) {
            acc[m].x += pm[m] * e.x; acc[m].y += pm[m] * e.y;
            acc[m].z += pm[m] * e.z; acc[m].w += pm[m] * e.w;
        }
        i = in;
    }

    // reduce row-halves: lanes l and l^32 share column c
#pragma unroll
    for (int m = 0; m < Mn; ++m) {
        acc[m].x += __shfl_xor(acc[m].x, 32);
        acc[m].y += __shfl_xor(acc[m].y, 32);
        acc[m].z += __shfl_xor(acc[m].z, 32);
        acc[m].w += __shfl_xor(acc[m].w, 32);
    }
    __shared__ float4 red[4 * Mn * 32];   // 32 KB, used only after the loop
    if (lane < 32) {
#pragma unroll
        for (int m = 0; m < Mn; ++m) red[(wv * Mn + m) * 32 + c] = acc[m];
    }
    __syncthreads();
#pragma unroll
    for (int r = 0; r < 2; ++r) {
        const int idx = t + r * 256;          // 0..511 -> (m = idx>>5, a = idx&31)
        const int m = idx >> 5, a = idx & 31;
        const float4 s0 = red[(0 * Mn + m) * 32 + a];
        const float4 s1 = red[(1 * Mn + m) * 32 + a];
        const float4 s2 = red[(2 * Mn + m) * 32 + a];
        const float4 s3 = red[(3 * Mn + m) * 32 + a];
        const float4 s = make_float4(s0.x + s1.x + s2.x + s3.x,
                                     s0.y + s1.y + s2.y + s3.y,
                                     s0.z + s1.z + s2.z + s3.z,
                                     s0.w + s1.w + s2.w + s3.w);
        if (mode == 0) {
            ((float4*)part)[(size_t)blockIdx.x * 512 + idx] = s;   // coalesced
        } else {
            float* dst = &PhiP[(size_t)m * An + a * 4];
            atomicAdd(dst + 0, s.x); atomicAdd(dst + 1, s.y);
            atomicAdd(dst + 2, s.z); atomicAdd(dst + 3, s.w);
        }
    }
}

// ---------------------------------------------------------------------------
// K1c: PhiP[m*128+a] = sum_k part[k][m*128+a].  grid (Mn, 8) x 128.
// Deterministic per-k-chunk sums, 8 atomics per output address.
// ---------------------------------------------------------------------------
__global__ __launch_bounds__(128) void k_red(const float* __restrict__ part,
                                             float* __restrict__ PhiP) {
    const int m = blockIdx.x;
    const int kc = blockIdx.y;
    const int a = threadIdx.x;
    constexpr int KCH = PHIP_BLOCKS / 8;   // 128
    float s = 0.f;
    const float* src = part + (size_t)kc * KCH * (Mn * An) + (size_t)m * An + a;
    for (int k = 0; k < KCH; ++k) s += src[(size_t)k * (Mn * An)];
    atomicAdd(&PhiP[(size_t)m * An + a], s);
}

// ---------------------------------------------------------------------------
// K1-fallback (small ws): round-2 structure, reads phi directly, owns sizeP.
// ---------------------------------------------------------------------------
__global__ __launch_bounds__(256) void k_phip_fb(const float* __restrict__ phi,
                                                 const float* __restrict__ E,
                                                 float* __restrict__ PhiP,
                                                 float* __restrict__ sizeP) {
    __shared__ float pv[64 * 16];
    __shared__ float szl[Mn];
    const int t = threadIdx.x;
    const int a4 = t & 31;
    const int g = t >> 5;
    const int vloc = t >> 2;
    const int mbase = 4 * (t & 3);

    if (t < Mn) szl[t] = 0.f;

    float4 acc0 = make_float4(0.f, 0.f, 0.f, 0.f);
    float4 acc1 = make_float4(0.f, 0.f, 0.f, 0.f);
    float4 szacc = make_float4(0.f, 0.f, 0.f, 0.f);

    for (int v0 = blockIdx.x * 64; v0 < Vn; v0 += gridDim.x * 64) {
        __syncthreads();
        const int v = v0 + vloc;
        float4 pj = make_float4(0.f, 0.f, 0.f, 0.f);
        if (v < Vn) {
            pj.x = sigm(phi[(size_t)(mbase + 0) * Vn + v]);
            pj.y = sigm(phi[(size_t)(mbase + 1) * Vn + v]);
            pj.z = sigm(phi[(size_t)(mbase + 2) * Vn + v]);
            pj.w = sigm(phi[(size_t)(mbase + 3) * Vn + v]);
        }
        *(float4*)&pv[4 * t] = pj;
        szacc.x += pj.x; szacc.y += pj.y; szacc.z += pj.z; szacc.w += pj.w;
        __syncthreads();
        const int vmax = min(64, Vn - v0);
#pragma unroll 8
        for (int vv = 0; vv < vmax; ++vv) {
            const float4 e = *(const float4*)&E[(size_t)(v0 + vv) * An + a4 * 4];
            const float2 pm = *(const float2*)&pv[vv * 16 + g * 2];
            acc0.x += pm.x * e.x; acc0.y += pm.x * e.y; acc0.z += pm.x * e.z; acc0.w += pm.x * e.w;
            acc1.x += pm.y * e.x; acc1.y += pm.y * e.y; acc1.z += pm.y * e.z; acc1.w += pm.y * e.w;
        }
    }
    {
        float* d0 = &PhiP[(size_t)(2 * g + 0) * An + a4 * 4];
        float* d1 = &PhiP[(size_t)(2 * g + 1) * An + a4 * 4];
        atomicAdd(d0 + 0, acc0.x); atomicAdd(d0 + 1, acc0.y);
        atomicAdd(d0 + 2, acc0.z); atomicAdd(d0 + 3, acc0.w);
        atomicAdd(d1 + 0, acc1.x); atomicAdd(d1 + 1, acc1.y);
        atomicAdd(d1 + 2, acc1.z); atomicAdd(d1 + 3, acc1.w);
    }
    atomicAdd(&szl[mbase + 0], szacc.x);
    atomicAdd(&szl[mbase + 1], szacc.y);
    atomicAdd(&szl[mbase + 2], szacc.z);
    atomicAdd(&szl[mbase + 3], szacc.w);
    __syncthreads();
    if (t < Mn) atomicAdd(&sizeP[t], szl[t]);
}

// ---------------------------------------------------------------------------
// K2: PhiQ[b,a] = sum_{i in seg b} E[qid[i],a];  sumpS[b,m] = sum_i pT[qid[i],m]
// grid (64 splits, B). block 256.
// ---------------------------------------------------------------------------
__global__ __launch_bounds__(256) void k_phiq(const int* __restrict__ qid,
                                              const int* __restrict__ offs,
                                              const float* __restrict__ E,
                                              const float* __restrict__ phi,
                                              const float* __restrict__ pT,
                                              int usepT,
                                              float* __restrict__ PhiQ,
                                              float* __restrict__ sumpS) {
    const int b = blockIdx.y;
    const int s0 = offs[b], s1 = offs[b + 1];
    const int len = s1 - s0;
    const int nsplit = (int)gridDim.x;
    const int chunk = (len + nsplit - 1) / nsplit;
    const int start = s0 + (int)blockIdx.x * chunk;
    const int end = min(start + chunk, s1);
    const int t = threadIdx.x;

    __shared__ float phl[8 * 128];
    __shared__ float sP[Mn];
    if (t < Mn) sP[t] = 0.f;

    {
        const int a4 = t & 31, sub = t >> 5;
        float4 acc = make_float4(0.f, 0.f, 0.f, 0.f);
        const float4* E4 = (const float4*)E;
        int i = start + sub;
        for (; i + 24 < end; i += 32) {
            const int q0 = qid[i], q1 = qid[i + 8], q2 = qid[i + 16], q3 = qid[i + 24];
            const float4 e0 = E4[(size_t)q0 * 32 + a4];
            const float4 e1 = E4[(size_t)q1 * 32 + a4];
            const float4 e2 = E4[(size_t)q2 * 32 + a4];
            const float4 e3 = E4[(size_t)q3 * 32 + a4];
            acc.x += e0.x + e1.x + e2.x + e3.x;
            acc.y += e0.y + e1.y + e2.y + e3.y;
            acc.z += e0.z + e1.z + e2.z + e3.z;
            acc.w += e0.w + e1.w + e2.w + e3.w;
        }
        for (; i < end; i += 8) {
            const float4 e = E4[(size_t)qid[i] * 32 + a4];
            acc.x += e.x; acc.y += e.y; acc.z += e.z; acc.w += e.w;
        }
        *(float4*)&phl[sub * 128 + a4 * 4] = acc;
    }
    __syncthreads();
    if (t < 128) {
        float s = 0.f;
#pragma unroll
        for (int k = 0; k < 8; ++k) s += phl[k * 128 + t];
        atomicAdd(&PhiQ[(size_t)b * An + t], s);
    }

    float4 acc = make_float4(0.f, 0.f, 0.f, 0.f);
    const int m4 = t & 3, io = t >> 2;
    if (usepT) {
        const float4* pT4 = (const float4*)pT;
        int i = start + io;
        for (; i + 192 < end; i += 256) {
            const int q0 = qid[i], q1 = qid[i + 64], q2 = qid[i + 128], q3 = qid[i + 192];
            const float4 p0 = pT4[(size_t)q0 * 4 + m4];
            const float4 p1 = pT4[(size_t)q1 * 4 + m4];
            const float4 p2 = pT4[(size_t)q2 * 4 + m4];
            const float4 p3 = pT4[(size_t)q3 * 4 + m4];
            acc.x += p0.x + p1.x + p2.x + p3.x;
            acc.y += p0.y + p1.y + p2.y + p3.y;
            acc.z += p0.z + p1.z + p2.z + p3.z;
            acc.w += p0.w + p1.w + p2.w + p3.w;
        }
        for (; i < end; i += 64) {
            const float4 p = pT4[(size_t)qid[i] * 4 + m4];
            acc.x += p.x; acc.y += p.y; acc.z += p.z; acc.w += p.w;
        }
    } else {
        for (int i = start + io; i < end; i += 64) {
            const int q = qid[i];
            acc.x += sigm(phi[(size_t)(m4 * 4 + 0) * Vn + q]);
            acc.y += sigm(phi[(size_t)(m4 * 4 + 1) * Vn + q]);
            acc.z += sigm(phi[(size_t)(m4 * 4 + 2) * Vn + q]);
            acc.w += sigm(phi[(size_t)(m4 * 4 + 3) * Vn + q]);
        }
    }
#pragma unroll
    for (int off = 32; off >= 4; off >>= 1) {
        acc.x += __shfl_xor(acc.x, off);
        acc.y += __shfl_xor(acc.y, off);
        acc.z += __shfl_xor(acc.z, off);
        acc.w += __shfl_xor(acc.w, off);
    }
    if ((t & 63) < 4) {
        atomicAdd(&sP[m4 * 4 + 0], acc.x);
        atomicAdd(&sP[m4 * 4 + 1], acc.y);
        atomicAdd(&sP[m4 * 4 + 2], acc.z);
        atomicAdd(&sP[m4 * 4 + 3], acc.w);
    }
    __syncthreads();
    if (t < Mn) atomicAdd(&sumpS[(size_t)b * Mn + t], sP[t]);
}

// ---------------------------------------------------------------------------
// K3: per-b block (128 thr): BP, Vp, AQ, scores, softmax, Z, C[b,h,:]
// ---------------------------------------------------------------------------
__global__ __launch_bounds__(128) void k_small(const float* __restrict__ PhiP,
                                               const float* __restrict__ sizeP,
                                               const float* __restrict__ PhiQ,
                                               const float* __restrict__ sumpS,
                                               const int* __restrict__ offs,
                                               const float* __restrict__ W_A,
                                               const float* __restrict__ W_B,
                                               const float* __restrict__ W_val,
                                               const float* __restrict__ b_val,
                                               const float* __restrict__ W_out,
                                               const float* __restrict__ size_w,
                                               float* __restrict__ Cws) {
    const int b = blockIdx.x;
    const int i = threadIdx.x;
    __shared__ float BP[Mn * An];
    __shared__ float Vp[Mn * HDn];
    __shared__ float AQs[An];
    __shared__ float sc[Mn];
    __shared__ float attn[Mn];
    __shared__ float Zs[HDn];

    {
        const float4* wa = (const float4*)(W_A + (size_t)i * An);
        const float4* pq = (const float4*)(PhiQ + (size_t)b * An);
        float aq = 0.f;
        for (int q = 0; q < An / 4; ++q) {
            const float4 w = wa[q], p = pq[q];
            aq += w.x * p.x + w.y * p.y + w.z * p.z + w.w * p.w;
        }
        AQs[i] = aq;
    }
    {
        const float4* wb = (const float4*)(W_B + (size_t)i * An);
        for (int m = 0; m < Mn; ++m) {
            const float4* pp = (const float4*)(PhiP + (size_t)m * An);
            float s = 0.f;
            for (int q = 0; q < An / 4; ++q) {
                const float4 w = wb[q], p = pp[q];
                s += w.x * p.x + w.y * p.y + w.z * p.z + w.w * p.w;
            }
            BP[m * An + i] = s;
        }
    }
    if (i < HDn) {
        const float4* wv = (const float4*)(W_val + (size_t)i * An);
        for (int m = 0; m < Mn; ++m) {
            const float4* pp = (const float4*)(PhiP + (size_t)m * An);
            float s = 0.f;
            for (int q = 0; q < An / 4; ++q) {
                const float4 w = wv[q], p = pp[q];
                s += w.x * p.x + w.y * p.y + w.z * p.z + w.w * p.w;
            }
            Vp[m * HDn + i] = s + b_val[i];
        }
    }
    __syncthreads();

    const float szQ = (float)(offs[b + 1] - offs[b]);
    if (i < Mn) {
        float d = 0.f;
        for (int a = 0; a < An; ++a) d += AQs[a] * BP[i * An + a];
        const float delta = szQ + sizeP[i] - 2.f * sumpS[(size_t)b * Mn + i];
        sc[i] = -GAMMA * delta + BETA * d + size_w[0] * szQ + size_w[1] * sizeP[i];
    }
    __syncthreads();
    if (i < Mn) {
        float mx = sc[0];
        for (int m = 1; m < Mn; ++m) mx = fmaxf(mx, sc[m]);
        float sum = 0.f;
        for (int m = 0; m < Mn; ++m) sum += __expf(sc[m] - mx);
        attn[i] = __expf(sc[i] - mx) / sum;
    }
    __syncthreads();
    if (i < HDn) {
        float z = 0.f;
        for (int m = 0; m < Mn; ++m) z += attn[m] * Vp[m * HDn + i];
        Zs[i] = z;
    }
    __syncthreads();
    {
        const float* wo = W_out + (size_t)i * Dn;
#pragma unroll
        for (int h = 0; h < Hn; ++h) {
            float c = 0.f;
#pragma unroll
            for (int j = 0; j < HDn; ++j) c += Zs[j] * wo[h * HDn + j];
            Cws[((size_t)b * Hn + h) * Dn + i] = c;
        }
    }
}

// ---------------------------------------------------------------------------
// K4: out[b,l,:] = b_out + sum_h softmax_h(ts[b,l,:].W_gate[h]+b_gate) * C[b,h,:]
// ---------------------------------------------------------------------------
__global__ __launch_bounds__(256) void k_out(const float* __restrict__ ts,
                                             const float* __restrict__ W_gate,
                                             const float* __restrict__ b_gate,
                                             const float* __restrict__ b_out,
                                             const float* __restrict__ Cws,
                                             float* __restrict__ out) {
    constexpr int CHUNK = 128;
    const int b = blockIdx.y;
    const int t = threadIdx.x;
    __shared__ float4 WgS[Hn * 32];
    __shared__ float4 CS[Hn * 32];
    __shared__ float4 boS[32];
    __shared__ float bgS[Hn];
    if (t < 128) WgS[t] = ((const float4*)W_gate)[t];
    else CS[t - 128] = ((const float4*)(Cws + (size_t)b * Hn * Dn))[t - 128];
    if (t < 32) boS[t] = ((const float4*)b_out)[t];
    if (t >= 64 && t < 64 + Hn) bgS[t - 64] = b_gate[t - 64];
    __syncthreads();

    const int sl = t & 31;
    const int tg = t >> 5;
    const size_t rowbase = (size_t)b * Ln + (size_t)blockIdx.x * CHUNK;
    const float4* x4 = (const float4*)ts + rowbase * 32;
    float4* o4 = (float4*)out + rowbase * 32;

    const float4 w0 = WgS[0 * 32 + sl], w1 = WgS[1 * 32 + sl];
    const float4 w2 = WgS[2 * 32 + sl], w3 = WgS[3 * 32 + sl];
    const float4 c0 = CS[0 * 32 + sl], c1 = CS[1 * 32 + sl];
    const float4 c2 = CS[2 * 32 + sl], c3 = CS[3 * 32 + sl];
    const float4 bo = boS[sl];
    const float bg0 = bgS[0], bg1 = bgS[1], bg2 = bgS[2], bg3 = bgS[3];

    for (int it = 0; it < CHUNK / 8; ++it) {
        const int tok = it * 8 + tg;
        const float4 x = x4[(size_t)tok * 32 + sl];
        float a0 = x.x * w0.x + x.y * w0.y + x.z * w0.z + x.w * w0.w;
        float a1 = x.x * w1.x + x.y * w1.y + x.z * w1.z + x.w * w1.w;
        float a2 = x.x * w2.x + x.y * w2.y + x.z * w2.z + x.w * w2.w;
        float a3 = x.x * w3.x + x.y * w3.y + x.z * w3.z + x.w * w3.w;
#pragma unroll
        for (int off = 16; off > 0; off >>= 1) {
            a0 += __shfl_xor(a0, off);
            a1 += __shfl_xor(a1, off);
            a2 += __shfl_xor(a2, off);
            a3 += __shfl_xor(a3, off);
        }
        a0 += bg0; a1 += bg1; a2 += bg2; a3 += bg3;
        const float mx = fmaxf(fmaxf(a0, a1), fmaxf(a2, a3));
        const float e0 = __expf(a0 - mx), e1 = __expf(a1 - mx);
        const float e2 = __expf(a2 - mx), e3 = __expf(a3 - mx);
        const float inv = 1.f / (e0 + e1 + e2 + e3);
        const float g0 = e0 * inv, g1 = e1 * inv, g2 = e2 * inv, g3 = e3 * inv;
        float4 o = bo;
        o.x += g0 * c0.x + g1 * c1.x + g2 * c2.x + g3 * c3.x;
        o.y += g0 * c0.y + g1 * c1.y + g2 * c2.y + g3 * c3.y;
        o.z += g0 * c0.z + g1 * c1.z + g2 * c2.z + g3 * c3.z;
        o.w += g0 * c0.w + g1 * c1.w + g2 * c2.w + g3 * c3.w;
        o4[(size_t)tok * 32 + sl] = o;
    }
}

extern "C" void kernel_launch(void* const* d_in, const int* in_sizes, int n_in,
                              void* d_out, int out_size, void* d_ws, size_t ws_size,
                              hipStream_t stream) {
    const float* ts     = (const float*)d_in[0];
    const int*   qid    = (const int*)d_in[1];
    const int*   offs   = (const int*)d_in[2];
    const float* E      = (const float*)d_in[3];
    const float* phi    = (const float*)d_in[4];
    const float* W_A    = (const float*)d_in[5];
    const float* W_B    = (const float*)d_in[6];
    const float* W_val  = (const float*)d_in[7];
    const float* b_val  = (const float*)d_in[8];
    const float* W_gate = (const float*)d_in[9];
    const float* b_gate = (const float*)d_in[10];
    const float* W_out  = (const float*)d_in[11];
    const float* b_out  = (const float*)d_in[12];
    const float* size_w = (const float*)d_in[13];
    float* out = (float*)d_out;
    float* ws  = (float*)d_ws;

    float* PhiP  = ws + OFF_PHIP;
    float* sizeP = ws + OFF_SIZEP;
    float* PhiQ  = ws + OFF_PHIQ;
    float* sumpS = ws + OFF_SUMPS;
    float* Cws   = ws + OFF_C;
    float* pT    = ws + OFF_PT;
    float* part  = ws + OFF_PART;
    const int usepT   = (ws_size >= WS_FLOATS_PT * sizeof(float)) ? 1 : 0;
    const int usePart = (ws_size >= WS_FLOATS_PART * sizeof(float)) ? 1 : 0;

    hipMemsetAsync(ws, 0, OFF_C * sizeof(float), stream);  // zero accumulators
    if (usepT) {
        k_pt<<<dim3((Vn + 255) / 256), dim3(256), 0, stream>>>(phi, pT, sizeP);
        k_phip<<<dim3(PHIP_BLOCKS), dim3(256), 0, stream>>>(E, pT, PhiP, part,
                                                            usePart ? 0 : 1);
        if (usePart)
            k_red<<<dim3(Mn, 8), dim3(128), 0, stream>>>(part, PhiP);
    } else {
        k_phip_fb<<<dim3(512), dim3(256), 0, stream>>>(phi, E, PhiP, sizeP);
    }
    k_phiq<<<dim3(64, Bn), dim3(256), 0, stream>>>(qid, offs, E, phi, pT, usepT, PhiQ, sumpS);
    k_small<<<dim3(Bn), dim3(128), 0, stream>>>(PhiP, sizeP, PhiQ, sumpS, offs,
                                                W_A, W_B, W_val, b_val, W_out, size_w, Cws);
    k_out<<<dim3(Ln / 128, Bn), dim3(256), 0, stream>>>(ts, W_gate, b_gate, b_out, Cws, out);
}